// Round 2
// baseline (309.482 us; speedup 1.0000x reference)
//
#include <hip/hip_runtime.h>
#include <hip/hip_bf16.h>

#define SEQ_T 100
#define HID 20
#define G3 60           // 3*HID, gate columns z[0:20) r[20:40) h[40:60)
#define EMB_D 50
#define ROWP 64         // padded table2 row stride (floats)
#define VOCAB_N 50000

typedef float v2f __attribute__((ext_vector_type(2)));

__device__ __forceinline__ float b2f(__hip_bfloat16 v) { return __bfloat162float(v); }

// dtype-agnostic load: isf=1 -> fp32 data, isf=0 -> bf16 data
__device__ __forceinline__ float ldf(const void* p, int i, int isf) {
  return isf ? ((const float*)p)[i]
             : __bfloat162float(((const __hip_bfloat16*)p)[i]);
}

// Classify tensor dtype by scanning the first 8192 halfwords of emb_table.
// bf16 N(0,0.05) data: exponent field <= ~124. fp32 data: low halfwords have
// uniform-random exponent fields -> some >= 200 with probability ~1.
__global__ __launch_bounds__(256) void detect_dtype(
    const unsigned short* __restrict__ h, int* __restrict__ flag)
{
  __shared__ int s;
  if (threadIdx.x == 0) s = 0;
  __syncthreads();
  int big = 0;
#pragma unroll
  for (int i = 0; i < 32; ++i) {
    unsigned short u = h[threadIdx.x * 32 + i];
    int e = (u >> 7) & 0xFF;
    big |= (e >= 200);
  }
  if (big) atomicOr(&s, 1);
  __syncthreads();
  if (threadIdx.x == 0) *flag = s;   // 1 = fp32, 0 = bf16
}

// tab[v][j] = bi1[j] + sum_k emb[v][k] * W1[k][j]   (fp32, row padded to 64)
__global__ __launch_bounds__(256) void build_table(
    const void* __restrict__ emb,
    const void* __restrict__ W1,
    const void* __restrict__ b1,
    const int* __restrict__ flag,
    float* __restrict__ tab)
{
  const int isf = *flag;
  int lane = threadIdx.x & 63;
  int v = blockIdx.x * 4 + (threadIdx.x >> 6);
  if (v >= VOCAB_N) return;
  float acc = 0.f;
  if (lane < G3) {
    acc = ldf(b1, lane, isf);                    // b1[0] = input bias
    const int base = v * EMB_D;
#pragma unroll 10
    for (int k = 0; k < EMB_D; ++k)
      acc = fmaf(ldf(emb, base + k, isf), ldf(W1, k * G3 + lane, isf), acc);
  }
  tab[(size_t)v * ROWP + lane] = acc;            // pad cols 60..63 = 0
}

// One wave per block; each wave runs 2 batch elements (float2-packed).
// lane j < 60 owns gate column j. h-state broadcast via LDS; r/hcand via shfl.
template <bool USE_TAB>
__global__ __launch_bounds__(64) void gru_main(
    const int* __restrict__ x,
    const float* __restrict__ tab,
    const void* __restrict__ emb,
    const void* __restrict__ W1,
    const void* __restrict__ U1,
    const void* __restrict__ b1,
    const void* __restrict__ W2,
    const void* __restrict__ U2,
    const void* __restrict__ b2,
    const void* __restrict__ Wd,
    const void* __restrict__ bd,
    const int* __restrict__ flag,
    void* __restrict__ out)
{
  const int isf = *flag;
  const int j = threadIdx.x;
  const int jc = j < G3 ? j : G3 - 1;    // clamp for weight loads (lanes 60..63)
  const int b0 = blockIdx.x * 2;

  // per-lane weight columns, duplicated {w,w} so <2 x float> math packs
  v2f wU1[HID], wW2[HID], wU2[HID];
#pragma unroll
  for (int k = 0; k < HID; ++k) {
    float a = ldf(U1, k * G3 + jc, isf); wU1[k] = (v2f){a, a};
    float c = ldf(W2, k * G3 + jc, isf); wW2[k] = (v2f){c, c};
    float d = ldf(U2, k * G3 + jc, isf); wU2[k] = (v2f){d, d};
  }
  const float br1 = ldf(b1, G3 + jc, isf);   // recurrent bias layer 1
  const float bi2 = ldf(b2, jc, isf);        // input bias layer 2
  const float br2 = ldf(b2, G3 + jc, isf);   // recurrent bias layer 2

  float w1c[EMB_D];                          // W1 column j (fallback path only)
  float bi1v = 0.f;
  if constexpr (!USE_TAB) {
    bi1v = ldf(b1, jc, isf);
#pragma unroll
    for (int k = 0; k < EMB_D; ++k) w1c[k] = ldf(W1, k * G3 + jc, isf);
  }

  __shared__ v2f h1s[HID], h2s[HID];
  __shared__ float e0[EMB_D], e1[EMB_D];     // fallback emb-row staging
  if (j < HID) { h1s[j] = (v2f){0.f, 0.f}; h2s[j] = (v2f){0.f, 0.f}; }
  __syncthreads();
  v2f h1r = (v2f){0.f, 0.f}, h2r = (v2f){0.f, 0.f};  // owner-lane register copy

  const int* __restrict__ x0 = x + (size_t)b0 * SEQ_T;
  const int* __restrict__ x1 = x0 + SEQ_T;

  // software-pipelined input transform (1 step ahead)
  v2f nmx = (v2f){0.f, 0.f};
  float r0 = 0.f, r1 = 0.f;
  if constexpr (USE_TAB) {
    int i0 = x0[0], i1 = x1[0];
    nmx.x = tab[i0 * ROWP + j];
    nmx.y = tab[i1 * ROWP + j];
  } else {
    int i0 = x0[0], i1 = x1[0];
    if (j < EMB_D) {
      r0 = ldf(emb, i0 * EMB_D + j, isf);
      r1 = ldf(emb, i1 * EMB_D + j, isf);
    }
  }

#pragma unroll 1
  for (int t = 0; t < SEQ_T; ++t) {
    v2f mx;
    if constexpr (USE_TAB) {
      mx = nmx;
      if (t + 1 < SEQ_T) {
        int p0 = x0[t + 1], p1 = x1[t + 1];
        nmx.x = tab[p0 * ROWP + j];
        nmx.y = tab[p1 * ROWP + j];
      }
    } else {
      __syncthreads();                       // prior step done reading e0/e1
      if (j < EMB_D) { e0[j] = r0; e1[j] = r1; }
      __syncthreads();
      if (t + 1 < SEQ_T) {                   // prefetch next rows into regs
        int p0 = x0[t + 1], p1 = x1[t + 1];
        if (j < EMB_D) {
          r0 = ldf(emb, p0 * EMB_D + j, isf);
          r1 = ldf(emb, p1 * EMB_D + j, isf);
        }
      }
      mx = (v2f){bi1v, bi1v};
#pragma unroll
      for (int k = 0; k < EMB_D; ++k) {
        mx.x = fmaf(e0[k], w1c[k], mx.x);
        mx.y = fmaf(e1[k], w1c[k], mx.y);
      }
    }

    // ---- GRU1: mh = h1 @ U1 + br1 ----
    v2f mh = (v2f){br1, br1};
#pragma unroll
    for (int k = 0; k < HID; ++k) mh += h1s[k] * wU1[k];   // broadcast LDS reads
    v2f m = mx + mh;
    v2f sg;                                                // sigmoid (z: lanes 0..19, r: 20..39)
    sg.x = __builtin_amdgcn_rcpf(1.f + __expf(-m.x));
    sg.y = __builtin_amdgcn_rcpf(1.f + __expf(-m.y));
    v2f rr;                                                // h-lanes fetch r from lane j-20
    rr.x = __shfl(sg.x, j - 20);
    rr.y = __shfl(sg.y, j - 20);
    v2f hp = mx + rr * mh;                                 // xh + r*(h@U_h + br_h)
    v2f hc;                                                // tanh
    hc.x = 1.f - 2.f * __builtin_amdgcn_rcpf(1.f + __expf(2.f * hp.x));
    hc.y = 1.f - 2.f * __builtin_amdgcn_rcpf(1.f + __expf(2.f * hp.y));
    v2f hcv;                                               // z-lanes fetch hcand from lane j+40
    hcv.x = __shfl(hc.x, j + 40);
    hcv.y = __shfl(hc.y, j + 40);
    v2f h1n = sg * h1r + ((v2f){1.f, 1.f} - sg) * hcv;     // valid in lanes 0..19
    __syncthreads();
    if (j < HID) { h1s[j] = h1n; h1r = h1n; }
    __syncthreads();

    // ---- GRU2 ----
    v2f mx2 = (v2f){bi2, bi2};
    v2f mh2 = (v2f){br2, br2};
#pragma unroll
    for (int k = 0; k < HID; ++k) {
      mx2 += h1s[k] * wW2[k];
      mh2 += h2s[k] * wU2[k];
    }
    v2f m2 = mx2 + mh2;
    v2f sg2;
    sg2.x = __builtin_amdgcn_rcpf(1.f + __expf(-m2.x));
    sg2.y = __builtin_amdgcn_rcpf(1.f + __expf(-m2.y));
    v2f rr2;
    rr2.x = __shfl(sg2.x, j - 20);
    rr2.y = __shfl(sg2.y, j - 20);
    v2f hp2 = mx2 + rr2 * mh2;
    v2f hc2;
    hc2.x = 1.f - 2.f * __builtin_amdgcn_rcpf(1.f + __expf(2.f * hp2.x));
    hc2.y = 1.f - 2.f * __builtin_amdgcn_rcpf(1.f + __expf(2.f * hp2.y));
    v2f hcv2;
    hcv2.x = __shfl(hc2.x, j + 40);
    hcv2.y = __shfl(hc2.y, j + 40);
    v2f h2n = sg2 * h2r + ((v2f){1.f, 1.f} - sg2) * hcv2;
    __syncthreads();
    if (j < HID) { h2s[j] = h2n; h2r = h2n; }
    __syncthreads();
  }

  // ---- dense: logits = h2 @ Wd + bd ----
  if (j < 15) {
    float bdj = ldf(bd, j, isf);
    v2f acc = (v2f){bdj, bdj};
#pragma unroll
    for (int k = 0; k < HID; ++k) {
      float w = ldf(Wd, k * 15 + j, isf);
      acc += h2s[k] * (v2f){w, w};
    }
    if (isf) {
      ((float*)out)[b0 * 15 + j]       = acc.x;
      ((float*)out)[(b0 + 1) * 15 + j] = acc.y;
    } else {
      ((__hip_bfloat16*)out)[b0 * 15 + j]       = __float2bfloat16(acc.x);
      ((__hip_bfloat16*)out)[(b0 + 1) * 15 + j] = __float2bfloat16(acc.y);
    }
  }
}

extern "C" void kernel_launch(void* const* d_in, const int* in_sizes, int n_in,
                              void* d_out, int out_size, void* d_ws, size_t ws_size,
                              hipStream_t stream) {
  const int* x    = (const int*)d_in[0];
  const void* emb = d_in[1];
  const void* W1  = d_in[2];
  const void* U1  = d_in[3];
  const void* b1  = d_in[4];
  const void* W2  = d_in[5];
  const void* U2  = d_in[6];
  const void* b2  = d_in[7];
  const void* Wd  = d_in[8];
  const void* bd  = d_in[9];

  int*   flag = (int*)d_ws;
  float* tab  = (float*)((char*)d_ws + 64);
  const size_t need = 64 + (size_t)VOCAB_N * ROWP * sizeof(float);

  detect_dtype<<<1, 256, 0, stream>>>((const unsigned short*)emb, flag);

  if (ws_size >= need) {
    build_table<<<(VOCAB_N + 3) / 4, 256, 0, stream>>>(emb, W1, b1, flag, tab);
    gru_main<true><<<8192 / 2, 64, 0, stream>>>(x, tab, emb, W1, U1, b1, W2, U2,
                                                b2, Wd, bd, flag, d_out);
  } else {
    gru_main<false><<<8192 / 2, 64, 0, stream>>>(x, tab, emb, W1, U1, b1, W2, U2,
                                                 b2, Wd, bd, flag, d_out);
  }
}